// Round 1
// baseline (176.196 us; speedup 1.0000x reference)
//
#include <hip/hip_runtime.h>

#define NC 19
#define NB (NC * NC)      // 361 joint-histogram bins
#define NCOPY 8           // one histogram copy per half-wave (32 lanes)
#define UNROLL 8          // 8 int4-pairs (16 loads, 256B/lane) in flight
#define EPS 1e-5f

// Kernel 1: joint histogram J[t*19+p] over all element pairs.
// Memory-latency-bound fix: 16 independent int4 loads in flight per thread
// + half-wave-private LDS copies (8 * 361 u32 = 11.5 KB).
__global__ __launch_bounds__(256, 4) void joint_hist_kernel(
    const int4* __restrict__ yp, const int4* __restrict__ yt,
    unsigned int* __restrict__ gJ, int n4)
{
    __shared__ unsigned int sJ[NCOPY * NB];
    const int tid = threadIdx.x;
    unsigned int* mine = &sJ[(tid >> 5) * NB];   // half-wave private copy

    for (int i = tid; i < NCOPY * NB; i += 256) sJ[i] = 0u;
    __syncthreads();

    const int nthreads = gridDim.x * 256;
    int i = blockIdx.x * 256 + tid;

    // Unrolled-by-8 grid-stride loop: all 16 loads are issued before any
    // consumption -> ~256 B/lane outstanding (vs 32 B before).
    for (; i + 7 * nthreads < n4; i += 8 * nthreads) {
        int4 p[UNROLL], t[UNROLL];
        #pragma unroll
        for (int u = 0; u < UNROLL; ++u) {
            p[u] = yp[i + u * nthreads];
            t[u] = yt[i + u * nthreads];
        }
        #pragma unroll
        for (int u = 0; u < UNROLL; ++u) {
            atomicAdd(&mine[t[u].x * NC + p[u].x], 1u);
            atomicAdd(&mine[t[u].y * NC + p[u].y], 1u);
            atomicAdd(&mine[t[u].z * NC + p[u].z], 1u);
            atomicAdd(&mine[t[u].w * NC + p[u].w], 1u);
        }
    }
    // Tail (not taken for n4 = 4M with grid 2048, kept for generality)
    for (; i < n4; i += nthreads) {
        int4 p = yp[i], t = yt[i];
        atomicAdd(&mine[t.x * NC + p.x], 1u);
        atomicAdd(&mine[t.y * NC + p.y], 1u);
        atomicAdd(&mine[t.z * NC + p.z], 1u);
        atomicAdd(&mine[t.w * NC + p.w], 1u);
    }
    __syncthreads();

    // Reduce the 8 half-wave copies, one device atomic per bin per block.
    for (int b = tid; b < NB; b += 256) {
        unsigned int v = 0;
        #pragma unroll
        for (int c = 0; c < NCOPY; ++c) v += sJ[c * NB + b];
        if (v) atomicAdd(&gJ[b], v);
    }
}

// Kernel 2: one wave. Lane c (<19) computes dice for class c from the joint
// histogram: inter = J[c][c], count_y = row sum, count_p = col sum.
__global__ __launch_bounds__(64) void dice_final_kernel(
    const unsigned int* __restrict__ gJ, float* __restrict__ out)
{
    const int lane = threadIdx.x;
    float dice = 0.0f;
    if (lane < NC) {
        float inter = (float)gJ[lane * NC + lane];
        float cy = 0.0f, cp = 0.0f;
        #pragma unroll
        for (int j = 0; j < NC; ++j) {
            cy += (float)gJ[lane * NC + j];
            cp += (float)gJ[j * NC + lane];
        }
        float uni = cy + cp - inter;
        dice = (2.0f * inter + EPS) / (uni + EPS);
    }
    // 64-lane shuffle reduction (lanes >= 19 contribute 0)
    #pragma unroll
    for (int off = 32; off > 0; off >>= 1)
        dice += __shfl_down(dice, off, 64);
    if (lane == 0) out[0] = 1.0f - dice / (float)NC;
}

extern "C" void kernel_launch(void* const* d_in, const int* in_sizes, int n_in,
                              void* d_out, int out_size, void* d_ws, size_t ws_size,
                              hipStream_t stream)
{
    const int4* yp = (const int4*)d_in[0];   // y_pred, int32
    const int4* yt = (const int4*)d_in[1];   // y,      int32
    unsigned int* gJ = (unsigned int*)d_ws;  // 361 u32 counters
    float* out = (float*)d_out;

    const int n = in_sizes[0];               // 16*1024*1024, divisible by 4
    const int n4 = n >> 2;

    // ws is poisoned to 0xAA before every timed launch — zero the counters.
    hipMemsetAsync(d_ws, 0, NB * sizeof(unsigned int), stream);

    const int grid = 2048;                   // 2048*256 threads: 8 int4/thread
    joint_hist_kernel<<<grid, 256, 0, stream>>>(yp, yt, gJ, n4);
    dice_final_kernel<<<1, 64, 0, stream>>>(gJ, out);
}

// Round 2
// 156.786 us; speedup vs baseline: 1.1238x; 1.1238x over previous
//
#include <hip/hip_runtime.h>

#define NC 19
#define NB (NC * NC)      // 361 joint-histogram bins
#define NCOPY 8           // one histogram copy per half-wave (32 lanes)
#define EPS 1e-5f
#define MAXG 512

// Kernel 1: joint histogram J[t*19+p]. LDS-atomic update (measured floor:
// ~1 lane-update/cyc/CU). Each block writes its 361-bin partial to its own
// workspace slice -> NO contended device atomics, NO memset needed.
__global__ __launch_bounds__(256, 4) void joint_hist_kernel(
    const int4* __restrict__ yp, const int4* __restrict__ yt,
    unsigned int* __restrict__ part, int n4)
{
    __shared__ unsigned int sJ[NCOPY * NB];
    const int tid = threadIdx.x;
    unsigned int* mine = &sJ[(tid >> 5) * NB];   // half-wave private copy

    for (int i = tid; i < NCOPY * NB; i += 256) sJ[i] = 0u;
    __syncthreads();

    const int nthreads = gridDim.x * 256;
    int i = blockIdx.x * 256 + tid;

    for (; i + 7 * nthreads < n4; i += 8 * nthreads) {
        int4 p[8], t[8];
        #pragma unroll
        for (int u = 0; u < 8; ++u) {
            p[u] = yp[i + u * nthreads];
            t[u] = yt[i + u * nthreads];
        }
        #pragma unroll
        for (int u = 0; u < 8; ++u) {
            atomicAdd(&mine[t[u].x * NC + p[u].x], 1u);
            atomicAdd(&mine[t[u].y * NC + p[u].y], 1u);
            atomicAdd(&mine[t[u].z * NC + p[u].z], 1u);
            atomicAdd(&mine[t[u].w * NC + p[u].w], 1u);
        }
    }
    for (; i < n4; i += nthreads) {       // tail (empty for n4=4M, G=512)
        int4 p = yp[i], t = yt[i];
        atomicAdd(&mine[t.x * NC + p.x], 1u);
        atomicAdd(&mine[t.y * NC + p.y], 1u);
        atomicAdd(&mine[t.z * NC + p.z], 1u);
        atomicAdd(&mine[t.w * NC + p.w], 1u);
    }
    __syncthreads();

    // Combine the 8 half-wave copies; write this block's partial (coalesced).
    unsigned int* my_part = part + blockIdx.x * NB;
    for (int b = tid; b < NB; b += 256) {
        unsigned int v = 0;
        #pragma unroll
        for (int c = 0; c < NCOPY; ++c) v += sJ[c * NB + b];
        my_part[b] = v;
    }
}

// Kernel 2: one 1024-thread block. Threads 0..721 reduce the G partials
// (2 threads per bin, each half the block range, 8 independent load streams
// for MLP). Then wave 0 computes dice from the LDS joint histogram.
__global__ __launch_bounds__(1024) void dice_final_kernel(
    const unsigned int* __restrict__ part, float* __restrict__ out, int G)
{
    __shared__ unsigned int J[NB];
    const int tid = threadIdx.x;
    const int half = G >> 1;

    unsigned int s = 0;
    int bin = 0;
    if (tid < 2 * NB) {
        bin = (tid < NB) ? tid : tid - NB;
        const int b0 = (tid < NB) ? 0 : half;
        const int b1 = (tid < NB) ? half : G;
        unsigned int a0 = 0, a1 = 0, a2 = 0, a3 = 0, a4 = 0, a5 = 0, a6 = 0, a7 = 0;
        int b = b0;
        for (; b + 7 < b1; b += 8) {
            a0 += part[(b + 0) * NB + bin];
            a1 += part[(b + 1) * NB + bin];
            a2 += part[(b + 2) * NB + bin];
            a3 += part[(b + 3) * NB + bin];
            a4 += part[(b + 4) * NB + bin];
            a5 += part[(b + 5) * NB + bin];
            a6 += part[(b + 6) * NB + bin];
            a7 += part[(b + 7) * NB + bin];
        }
        for (; b < b1; ++b) a0 += part[b * NB + bin];
        s = ((a0 + a1) + (a2 + a3)) + ((a4 + a5) + (a6 + a7));
    }
    if (tid < NB) J[bin] = s;
    __syncthreads();
    if (tid >= NB && tid < 2 * NB) J[bin] += s;   // unique bin per thread: no race
    __syncthreads();

    if (tid < 64) {
        float dice = 0.0f;
        if (tid < NC) {
            float inter = (float)J[tid * NC + tid];
            float cy = 0.0f, cp = 0.0f;
            #pragma unroll
            for (int j = 0; j < NC; ++j) {
                cy += (float)J[tid * NC + j];
                cp += (float)J[j * NC + tid];
            }
            float uni = cy + cp - inter;
            dice = (2.0f * inter + EPS) / (uni + EPS);
        }
        #pragma unroll
        for (int off = 32; off > 0; off >>= 1)
            dice += __shfl_down(dice, off, 64);
        if (tid == 0) out[0] = 1.0f - dice / (float)NC;
    }
}

extern "C" void kernel_launch(void* const* d_in, const int* in_sizes, int n_in,
                              void* d_out, int out_size, void* d_ws, size_t ws_size,
                              hipStream_t stream)
{
    const int4* yp = (const int4*)d_in[0];   // y_pred, int32
    const int4* yt = (const int4*)d_in[1];   // y,      int32
    unsigned int* part = (unsigned int*)d_ws;
    float* out = (float*)d_out;

    const int n = in_sizes[0];               // 16*1024*1024, divisible by 4
    const int n4 = n >> 2;

    // Workspace holds G partial histograms (G*361*4 B). No memset needed:
    // every slot is written unconditionally by kernel 1.
    int G = MAXG;
    const int gmax = (int)(ws_size / (NB * sizeof(unsigned int)));
    if (gmax < G) G = gmax & ~1;             // keep G even for the 2-way reduce
    if (G < 2) G = 2;

    joint_hist_kernel<<<G, 256, 0, stream>>>(yp, yt, part, n4);
    dice_final_kernel<<<1, 1024, 0, stream>>>(part, out, G);
}